// Round 17
// baseline (1421.338 us; speedup 1.0000x reference)
//
#include <hip/hip_runtime.h>
#include <hip/hip_bf16.h>

#define DD 128

typedef __attribute__((ext_vector_type(8))) short short8;
typedef __attribute__((ext_vector_type(8))) unsigned short u16x8;
typedef __attribute__((ext_vector_type(4))) unsigned short u16x4;
typedef __attribute__((ext_vector_type(4))) float f32x4;

__device__ __forceinline__ unsigned short f2bf(float f) {
    union { unsigned int u; float f; } c; c.f = f;
    unsigned int u = c.u;
    unsigned int r = (u + 0x7FFFu + ((u >> 16) & 1u)) >> 16;
    return (unsigned short)r;
}
__device__ __forceinline__ float bf2f(unsigned short h) {
    union { unsigned int u; float f; } c; c.u = ((unsigned int)h) << 16; return c.f;
}

// -------- fused scatter (both directions in one launch, overlapped) --------
__device__ __forceinline__ void scatter_dir(const float* __restrict__ feats,
                                            const int* __restrict__ src,
                                            const int* __restrict__ dst,
                                            const float* __restrict__ u,
                                            unsigned int* __restrict__ pre,
                                            float* __restrict__ deg,
                                            int E, int wave, int lane, int nw)
{
    for (int e = wave; e < E; e += nw) {
        if (u[e] < 0.5f) {
            int s = src[e], d = dst[e];
            float2 x = *(const float2*)(feats + (size_t)s * DD + 2 * lane);
            unsigned int* p = pre + (size_t)d * 64 + lane;
#if defined(__HIP_DEVICE_COMPILE__)
            typedef short sv2 __attribute__((ext_vector_type(2)));
            sv2 v; v[0] = (short)f2bf(x.x); v[1] = (short)f2bf(x.y);
            __builtin_amdgcn_global_atomic_fadd_v2bf16((__attribute__((address_space(1))) sv2*)p, v);
#else
            (void)p; (void)x;
#endif
            if (lane == 0) unsafeAtomicAdd(deg + d, 1.0f);
        }
    }
}

__global__ void scatter2_kernel(const float* __restrict__ f1,
                                const int* __restrict__ s1, const int* __restrict__ d1,
                                const float* __restrict__ u1,
                                unsigned int* __restrict__ p1, float* __restrict__ g1, int E1,
                                const float* __restrict__ f2,
                                const int* __restrict__ s2, const int* __restrict__ d2,
                                const float* __restrict__ u2,
                                unsigned int* __restrict__ p2, float* __restrict__ g2, int E2)
{
    int half = gridDim.x >> 1;
    int lane = threadIdx.x & 63;
    int wavein = (blockIdx.x % half) * (blockDim.x >> 6) + (threadIdx.x >> 6);
    int nw = half * (blockDim.x >> 6);
    if (blockIdx.x < half) scatter_dir(f1, s1, d1, u1, p1, g1, E1, wavein, lane, nw);
    else                   scatter_dir(f2, s2, d2, u2, p2, g2, E2, wavein, lane, nw);
}

// -------- barrier-free table update; 16 waves/CU (launch_bounds(1024,1)) --------
// comb = X@Wself^T + bself + fmask*((pre/deg)@Wedge^T + (deg>0)*bedge)
// LN -> +residual -> SELU -> column-mask select
// Weights in LDS (bf16, XOR-swizzled). feats staged full-line to per-wave
// 4KB bf16 LDS tile (doubles as residual + output stage); pre fragment-direct
// plain loads. 1024-thread block, 1 block/CU -> 16 waves/CU, 128-VGPR cap.
__global__ __launch_bounds__(1024, 1)
void table_kernel(const float* __restrict__ feats,
                  const unsigned short* __restrict__ pre,   // bf16
                  const float* __restrict__ deg,
                  const float* __restrict__ Wself,
                  const float* __restrict__ bself,
                  const float* __restrict__ Wedge,
                  const float* __restrict__ bedge,
                  const float* __restrict__ lnw,
                  const float* __restrict__ lnb,
                  const float* __restrict__ ufeat,
                  float* __restrict__ out,
                  int N)
{
    __shared__ __align__(16) unsigned short wlds[2 * 16384];  // 64KB weights (bf16, swizzled)
    __shared__ __align__(16) char xsall[16 * 4096];           // 64KB: 16 waves x 4KB bf16 X tile

    const int tid = threadIdx.x;

    // ---- one-time weight staging: f32 -> bf16, XOR-swizzled (addr ^= (j&7)<<4) ----
    {
        int j   = tid >> 3;       // W row (output col) 0..127
        int kq8 = tid & 7;        // k eighth (16 elems)
        float fm = ufeat[j] < 0.3f ? 1.0f : 0.0f;
        const float* wsrow = Wself + j * DD + kq8 * 16;
        const float* werow = Wedge + j * DD + kq8 * 16;
        char* lbs = (char*)wlds;
        #pragma unroll
        for (int c = 0; c < 2; ++c) {
            unsigned short tS[8], tE[8];
            #pragma unroll
            for (int i = 0; i < 8; ++i) {
                tS[i] = f2bf(wsrow[c * 8 + i]);
                tE[i] = f2bf(werow[c * 8 + i] * fm);
            }
            int addr = (j * 256 + kq8 * 32 + c * 16) ^ ((j & 7) << 4);
            *(short8*)(lbs + addr)         = *(short8*)tS;
            *(short8*)(lbs + 32768 + addr) = *(short8*)tE;
        }
    }
    __syncthreads();   // only barrier in the kernel

    const int wave = tid >> 6;
    const int lane = tid & 63;
    const int lj = lane & 15;
    const int lk = lane >> 4;

    // per-lane column constants (col = ct*16 + lj)
    float bs[8], bem[8], lw[8], lb[8];
    unsigned fmask = 0;
    #pragma unroll
    for (int ct = 0; ct < 8; ++ct) {
        int col = ct * 16 + lj;
        bool fm = ufeat[col] < 0.3f;
        bs[ct]  = bself[col];
        bem[ct] = fm ? bedge[col] : 0.0f;
        lw[ct]  = lnw[col];
        lb[ct]  = lnb[col];
        fmask |= (fm ? 1u : 0u) << ct;
    }

    char* xs = xsall + wave * 4096;         // bf16 X tile [16][128]
    const char* wb = (const char*)wlds;
    const int ldb  = lj * 256 + lk * 16;
    const int xorv = (lj & 7) << 4;

    const int frow = lane >> 5;             // feats-load row parity
    const int fc4  = lane & 31;             // feats-load 16B chunk

    const int ntiles = N >> 4;
    for (int tile = blockIdx.x * 16 + wave; tile < ntiles; tile += gridDim.x * 16) {
        int row0 = tile << 4;
        int r = row0 + lj;

        // ---- feats: 8 full-line plain loads (2 rows x 32 lanes contiguous) ----
        #pragma unroll
        for (int j = 0; j < 8; ++j) {
            int row = j * 2 + frow;
            f32x4 v = *(const f32x4*)(feats + (size_t)(row0 + row) * DD + fc4 * 4);
            unsigned short t4[4];
            #pragma unroll
            for (int i = 0; i < 4; ++i) t4[i] = f2bf(v[i]);
            *(u16x4*)(xs + row * 256 + ((fc4 * 8) ^ ((row & 7) << 4))) = *(u16x4*)t4;
        }
        // ---- pre: fragment-direct plain loads ----
        u16x8 pv[4];
        #pragma unroll
        for (int t = 0; t < 4; ++t)
            pv[t] = *(const u16x8*)(pre + (size_t)r * DD + t * 32 + lk * 8);

        float dgr  = deg[r];
        float invd = 1.0f / fmaxf(dgr, 1.0f);
        float dpown = dgr > 0.5f ? 1.0f : 0.0f;

        // ---- fragments: xf from LDS, pf packed from direct loads ----
        short8 xf[4], pf[4];
        #pragma unroll
        for (int t = 0; t < 4; ++t) {
            xf[t] = *(const short8*)(xs + ((ldb + t * 64) ^ xorv));
            unsigned short tp[8];
            #pragma unroll
            for (int i = 0; i < 8; ++i) tp[i] = f2bf(bf2f(pv[t][i]) * invd);
            pf[t] = *(short8*)tp;
        }

        f32x4 acc[8];
        #pragma unroll
        for (int ct = 0; ct < 8; ++ct) { f32x4 z = {0.f,0.f,0.f,0.f}; acc[ct] = z; }

        #pragma unroll
        for (int t = 0; t < 4; ++t) {
            int a0 = (ldb + t * 64) ^ xorv;
            #pragma unroll
            for (int ct = 0; ct < 8; ++ct) {
                short8 ws = *(const short8*)(wb + ct * 4096 + a0);
                short8 we = *(const short8*)(wb + 32768 + ct * 4096 + a0);
                acc[ct] = __builtin_amdgcn_mfma_f32_16x16x32_bf16(xf[t], ws, acc[ct], 0, 0, 0);
                acc[ct] = __builtin_amdgcn_mfma_f32_16x16x32_bf16(pf[t], we, acc[ct], 0, 0, 0);
            }
        }

        // ---- epilogue; D layout: col = ct*16+lj, row-in-tile = lk*4+q ----
        #pragma unroll
        for (int q = 0; q < 4; ++q) {
            int rrl = lk * 4 + q;
            float degpos = __shfl(dpown, rrl, 64);   // lanes 0..15 hold rows 0..15
            float val[8];
            float s = 0.f, s2 = 0.f;
            #pragma unroll
            for (int ct = 0; ct < 8; ++ct) {
                float v = acc[ct][q] + bs[ct] + degpos * bem[ct];
                val[ct] = v; s += v; s2 += v * v;
            }
            #pragma unroll
            for (int m = 1; m < 16; m <<= 1) {
                s  += __shfl_xor(s,  m, 64);
                s2 += __shfl_xor(s2, m, 64);
            }
            float mu   = s * (1.0f / 128.0f);
            float var  = s2 * (1.0f / 128.0f) - mu * mu;
            float rstd = rsqrtf(var + 1e-5f);
            #pragma unroll
            for (int ct = 0; ct < 8; ++ct) {
                int col = ct * 16 + lj;
                int ra  = rrl * 256 + ((col * 2) ^ ((rrl & 7) << 4));
                float fres = bf2f(*(const unsigned short*)(xs + ra));
                float ln = (val[ct] - mu) * rstd * lw[ct] + lb[ct];
                float x = ln + fres;
                float selu = x > 0.f ? 1.0507009873554805f * x
                                     : 1.0507009873554805f * 1.6732632423543772f * (expf(x) - 1.0f);
                float o = ((fmask >> ct) & 1) ? selu : fres;
                *(unsigned short*)(xs + ra) = f2bf(o);   // in-place 2B
            }
        }

        // ---- full-line readback + plain vector stores (1KB contiguous/instr) ----
        #pragma unroll
        for (int j = 0; j < 8; ++j) {
            int row = j * 2 + frow;
            u16x4 ov = *(const u16x4*)(xs + row * 256 + ((fc4 * 8) ^ ((row & 7) << 4)));
            f32x4 o;
            #pragma unroll
            for (int i = 0; i < 4; ++i) o[i] = bf2f(ov[i]);
            *(f32x4*)(out + (size_t)(row0 + row) * DD + fc4 * 4) = o;
        }
    }
}

extern "C" void kernel_launch(void* const* d_in, const int* in_sizes, int n_in,
                              void* d_out, int out_size, void* d_ws, size_t ws_size,
                              hipStream_t stream)
{
    const float* feats_A = (const float*)d_in[0];
    const float* feats_B = (const float*)d_in[1];
    const float* W_p2c   = (const float*)d_in[2];
    const float* b_p2c   = (const float*)d_in[3];
    const float* W_c2p   = (const float*)d_in[4];
    const float* b_c2p   = (const float*)d_in[5];
    const float* Wself_A = (const float*)d_in[6];
    const float* bself_A = (const float*)d_in[7];
    const float* lnw_A   = (const float*)d_in[8];
    const float* lnb_A   = (const float*)d_in[9];
    const float* Wself_B = (const float*)d_in[10];
    const float* bself_B = (const float*)d_in[11];
    const float* lnw_B   = (const float*)d_in[12];
    const float* lnb_B   = (const float*)d_in[13];
    const float* u_p2c   = (const float*)d_in[14];
    const float* u_c2p   = (const float*)d_in[15];
    const float* u_featA = (const float*)d_in[16];
    const float* u_featB = (const float*)d_in[17];
    const int* src_p2c = (const int*)d_in[18];
    const int* dst_p2c = (const int*)d_in[19];
    const int* src_c2p = (const int*)d_in[20];
    const int* dst_c2p = (const int*)d_in[21];

    const int N_A = in_sizes[0] / DD;   // 200000
    const int N_B = in_sizes[1] / DD;   // 400000
    const int E1  = in_sizes[14];       // 800000
    const int E2  = in_sizes[15];       // 800000

    float* outA = (float*)d_out;
    float* outB = outA + (size_t)N_A * DD;

    // ws layout: pre_B (bf16), pre_A (bf16), deg_A (f32), deg_B (f32)
    const size_t preB_bytes = (size_t)N_B * DD * 2;   // 102.4MB
    const size_t preA_bytes = (size_t)N_A * DD * 2;   // 51.2MB
    const size_t need = preB_bytes + preA_bytes + (size_t)(N_A + N_B) * 4; // ~156MB
    if (ws_size < need) return;

    unsigned int*   preB_w = (unsigned int*)d_ws;
    unsigned int*   preA_w = (unsigned int*)((char*)d_ws + preB_bytes);
    float*          deg_A  = (float*)((char*)d_ws + preB_bytes + preA_bytes);
    float*          deg_B  = deg_A + N_A;
    const unsigned short* preB_h = (const unsigned short*)preB_w;
    const unsigned short* preA_h = (const unsigned short*)preA_w;

    (void)hipMemsetAsync(d_ws, 0, need, stream);

    // fused scatter: first half of grid does A->B, second half B->A (overlapped)
    dim3 sblk(256), sgrd(2048);
    scatter2_kernel<<<sgrd, sblk, 0, stream>>>(feats_A, src_p2c, dst_p2c, u_p2c, preB_w, deg_B, E1,
                                               feats_B, src_c2p, dst_c2p, u_c2p, preA_w, deg_A, E2);

    dim3 tblk(1024), tgrd(256);   // 1 block/CU, 16 waves/CU, 128-VGPR cap
    table_kernel<<<tgrd, tblk, 0, stream>>>(feats_A, preA_h, deg_A,
                                            Wself_A, bself_A, W_c2p, b_c2p,
                                            lnw_A, lnb_A, u_featA, outA, N_A);
    table_kernel<<<tgrd, tblk, 0, stream>>>(feats_B, preB_h, deg_B,
                                            Wself_B, bself_B, W_p2c, b_p2c,
                                            lnw_B, lnb_B, u_featB, outB, N_B);
}

// Round 18
// 1151.718 us; speedup vs baseline: 1.2341x; 1.2341x over previous
//
#include <hip/hip_runtime.h>
#include <hip/hip_bf16.h>

#define DD 128

typedef __attribute__((ext_vector_type(8))) short short8;
typedef __attribute__((ext_vector_type(8))) unsigned short u16x8;
typedef __attribute__((ext_vector_type(4))) float f32x4;

__device__ __forceinline__ unsigned short f2bf(float f) {
    union { unsigned int u; float f; } c; c.f = f;
    unsigned int u = c.u;
    unsigned int r = (u + 0x7FFFu + ((u >> 16) & 1u)) >> 16;
    return (unsigned short)r;
}
__device__ __forceinline__ float bf2f(unsigned short h) {
    union { unsigned int u; float f; } c; c.u = ((unsigned int)h) << 16; return c.f;
}

// -------- fused scatter (both directions in one launch, overlapped) --------
__device__ __forceinline__ void scatter_dir(const float* __restrict__ feats,
                                            const int* __restrict__ src,
                                            const int* __restrict__ dst,
                                            const float* __restrict__ u,
                                            unsigned int* __restrict__ pre,
                                            float* __restrict__ deg,
                                            int E, int wave, int lane, int nw)
{
    for (int e = wave; e < E; e += nw) {
        if (u[e] < 0.5f) {
            int s = src[e], d = dst[e];
            float2 x = *(const float2*)(feats + (size_t)s * DD + 2 * lane);
            unsigned int* p = pre + (size_t)d * 64 + lane;
#if defined(__HIP_DEVICE_COMPILE__)
            typedef short sv2 __attribute__((ext_vector_type(2)));
            sv2 v; v[0] = (short)f2bf(x.x); v[1] = (short)f2bf(x.y);
            __builtin_amdgcn_global_atomic_fadd_v2bf16((__attribute__((address_space(1))) sv2*)p, v);
#else
            (void)p; (void)x;
#endif
            if (lane == 0) unsafeAtomicAdd(deg + d, 1.0f);
        }
    }
}

__global__ void scatter2_kernel(const float* __restrict__ f1,
                                const int* __restrict__ s1, const int* __restrict__ d1,
                                const float* __restrict__ u1,
                                unsigned int* __restrict__ p1, float* __restrict__ g1, int E1,
                                const float* __restrict__ f2,
                                const int* __restrict__ s2, const int* __restrict__ d2,
                                const float* __restrict__ u2,
                                unsigned int* __restrict__ p2, float* __restrict__ g2, int E2)
{
    int half = gridDim.x >> 1;
    int lane = threadIdx.x & 63;
    int wavein = (blockIdx.x % half) * (blockDim.x >> 6) + (threadIdx.x >> 6);
    int nw = half * (blockDim.x >> 6);
    if (blockIdx.x < half) scatter_dir(f1, s1, d1, u1, p1, g1, E1, wavein, lane, nw);
    else                   scatter_dir(f2, s2, d2, u2, p2, g2, E2, wavein, lane, nw);
}

// -------- table update, TRANSPOSED MFMA (lane owns its own output row) --------
// comb = X@Wself^T + bself + fmask*((pre/deg)@Wedge^T + (deg>0)*bedge)
// LN -> +residual -> SELU -> column-mask select
// mfma(W_frag, X_frag) computes comb^T: lane (lj,lk) holds comb[row0+lj]
// [ct*16+lk*4 .. +3] as f32x4 -> no LDS transpose needed, row-local LN
// (2 shfl_xor across the 4 lk lanes), direct f32x4 residual re-read (L1-hit),
// contiguous f32x4 stores. LDS = 64KB weights + 2.5KB consts -> 2 blocks/CU,
// 16 waves/CU at 128 VGPR.
__global__ __launch_bounds__(512, 2)
void table_kernel(const float* __restrict__ feats,
                  const unsigned short* __restrict__ pre,   // bf16
                  const float* __restrict__ deg,
                  const float* __restrict__ Wself,
                  const float* __restrict__ bself,
                  const float* __restrict__ Wedge,
                  const float* __restrict__ bedge,
                  const float* __restrict__ lnw,
                  const float* __restrict__ lnb,
                  const float* __restrict__ ufeat,
                  float* __restrict__ out,
                  int N)
{
    __shared__ __align__(16) unsigned short wlds[2 * 16384];  // 64KB weights (bf16, swizzled)
    __shared__ __align__(16) float cbs[128];   // bself
    __shared__ __align__(16) float cbe[128];   // bedge * fmask
    __shared__ __align__(16) float clw[128];   // lnw
    __shared__ __align__(16) float clb[128];   // lnb
    __shared__ __align__(16) float cfm[128];   // fmask (1/0)

    const int tid = threadIdx.x;

    // ---- one-time weight staging: f32 -> bf16, XOR-swizzled (addr ^= (j&7)<<4) ----
    {
        int j  = tid >> 2;        // W row (output col) 0..127
        int kq = tid & 3;         // k quarter
        float fm = ufeat[j] < 0.3f ? 1.0f : 0.0f;
        const float* wsrow = Wself + j * DD + kq * 32;
        const float* werow = Wedge + j * DD + kq * 32;
        char* lbs = (char*)wlds;
        #pragma unroll
        for (int c = 0; c < 4; ++c) {
            unsigned short tS[8], tE[8];
            #pragma unroll
            for (int i = 0; i < 8; ++i) {
                tS[i] = f2bf(wsrow[c * 8 + i]);
                tE[i] = f2bf(werow[c * 8 + i] * fm);
            }
            int addr = (j * 256 + kq * 64 + c * 16) ^ ((j & 7) << 4);
            *(short8*)(lbs + addr)         = *(short8*)tS;
            *(short8*)(lbs + 32768 + addr) = *(short8*)tE;
        }
        if (kq == 0) {
            float f = ufeat[j] < 0.3f ? 1.0f : 0.0f;
            cbs[j] = bself[j];
            cbe[j] = bedge[j] * f;
            clw[j] = lnw[j];
            clb[j] = lnb[j];
            cfm[j] = f;
        }
    }
    __syncthreads();   // only barrier in the kernel

    const int lane = tid & 63;
    const int lj = lane & 15;     // this lane's OUTPUT ROW within tile
    const int lk = lane >> 4;     // col-chunk group (4 cols each)

    const char* wb = (const char*)wlds;
    const int ldb  = lj * 256 + lk * 16;   // weight-fragment address base
    const int xorv = (lj & 7) << 4;

    const int wave = tid >> 6;
    const int ntiles = N >> 4;
    for (int tile = blockIdx.x * 8 + wave; tile < ntiles; tile += gridDim.x * 8) {
        int row0 = tile << 4;
        int r = row0 + lj;
        const float* xrow = feats + (size_t)r * DD;

        // ---- X fragment: direct plain loads of own row ----
        f32x4 xr[8];
        #pragma unroll
        for (int t = 0; t < 4; ++t) {
            xr[2 * t]     = *(const f32x4*)(xrow + t * 32 + lk * 8);
            xr[2 * t + 1] = *(const f32x4*)(xrow + t * 32 + lk * 8 + 4);
        }
        // ---- pre fragment: direct plain loads of own row ----
        u16x8 pv[4];
        #pragma unroll
        for (int t = 0; t < 4; ++t)
            pv[t] = *(const u16x8*)(pre + (size_t)r * DD + t * 32 + lk * 8);

        float dgr  = deg[r];
        float invd = 1.0f / fmaxf(dgr, 1.0f);
        float degpos = dgr > 0.5f ? 1.0f : 0.0f;

        short8 xf[4], pf[4];
        #pragma unroll
        for (int t = 0; t < 4; ++t) {
            unsigned short tx[8], tp[8];
            #pragma unroll
            for (int i = 0; i < 4; ++i) {
                tx[i]     = f2bf(xr[2 * t][i]);
                tx[4 + i] = f2bf(xr[2 * t + 1][i]);
            }
            #pragma unroll
            for (int i = 0; i < 8; ++i) tp[i] = f2bf(bf2f(pv[t][i]) * invd);
            xf[t] = *(short8*)tx;
            pf[t] = *(short8*)tp;
        }

        // ---- MFMA with swapped operands: D = comb^T ----
        // lane (lj,lk): acc[ct][q] = comb[row0+lj][ct*16+lk*4+q]
        f32x4 acc[8];
        #pragma unroll
        for (int ct = 0; ct < 8; ++ct) { f32x4 z = {0.f,0.f,0.f,0.f}; acc[ct] = z; }

        #pragma unroll
        for (int t = 0; t < 4; ++t) {
            int a0 = (ldb + t * 64) ^ xorv;
            #pragma unroll
            for (int ct = 0; ct < 8; ++ct) {
                short8 ws = *(const short8*)(wb + ct * 4096 + a0);
                short8 we = *(const short8*)(wb + 32768 + ct * 4096 + a0);
                acc[ct] = __builtin_amdgcn_mfma_f32_16x16x32_bf16(ws, xf[t], acc[ct], 0, 0, 0);
                acc[ct] = __builtin_amdgcn_mfma_f32_16x16x32_bf16(we, pf[t], acc[ct], 0, 0, 0);
            }
        }

        // ---- row-local epilogue: bias, LN stats (2 shfl), LN+SELU, store ----
        float s = 0.f, s2 = 0.f;
        #pragma unroll
        for (int ct = 0; ct < 8; ++ct) {
            int c0 = ct * 16 + lk * 4;
            f32x4 b4  = *(const f32x4*)&cbs[c0];
            f32x4 be4 = *(const f32x4*)&cbe[c0];
            #pragma unroll
            for (int q = 0; q < 4; ++q) {
                float v = acc[ct][q] + b4[q] + degpos * be4[q];
                acc[ct][q] = v;
                s += v; s2 += v * v;
            }
        }
        s  += __shfl_xor(s, 16, 64);  s2 += __shfl_xor(s2, 16, 64);
        s  += __shfl_xor(s, 32, 64);  s2 += __shfl_xor(s2, 32, 64);
        float mu   = s * (1.0f / 128.0f);
        float var  = s2 * (1.0f / 128.0f) - mu * mu;
        float rstd = rsqrtf(var + 1e-5f);

        float* orow = out + (size_t)r * DD;
        #pragma unroll
        for (int ct = 0; ct < 8; ++ct) {
            int c0 = ct * 16 + lk * 4;
            f32x4 lw4 = *(const f32x4*)&clw[c0];
            f32x4 lb4 = *(const f32x4*)&clb[c0];
            f32x4 fm4 = *(const f32x4*)&cfm[c0];
            f32x4 fres = *(const f32x4*)(xrow + c0);   // L1-hit (lines read for xf)
            f32x4 o;
            #pragma unroll
            for (int q = 0; q < 4; ++q) {
                float ln = (acc[ct][q] - mu) * rstd * lw4[q] + lb4[q];
                float x  = ln + fres[q];
                float selu = x > 0.f ? 1.0507009873554805f * x
                                     : 1.0507009873554805f * 1.6732632423543772f * (expf(x) - 1.0f);
                o[q] = fm4[q] > 0.5f ? selu : fres[q];
            }
            *(f32x4*)(orow + c0) = o;
        }
    }
}

extern "C" void kernel_launch(void* const* d_in, const int* in_sizes, int n_in,
                              void* d_out, int out_size, void* d_ws, size_t ws_size,
                              hipStream_t stream)
{
    const float* feats_A = (const float*)d_in[0];
    const float* feats_B = (const float*)d_in[1];
    const float* W_p2c   = (const float*)d_in[2];
    const float* b_p2c   = (const float*)d_in[3];
    const float* W_c2p   = (const float*)d_in[4];
    const float* b_c2p   = (const float*)d_in[5];
    const float* Wself_A = (const float*)d_in[6];
    const float* bself_A = (const float*)d_in[7];
    const float* lnw_A   = (const float*)d_in[8];
    const float* lnb_A   = (const float*)d_in[9];
    const float* Wself_B = (const float*)d_in[10];
    const float* bself_B = (const float*)d_in[11];
    const float* lnw_B   = (const float*)d_in[12];
    const float* lnb_B   = (const float*)d_in[13];
    const float* u_p2c   = (const float*)d_in[14];
    const float* u_c2p   = (const float*)d_in[15];
    const float* u_featA = (const float*)d_in[16];
    const float* u_featB = (const float*)d_in[17];
    const int* src_p2c = (const int*)d_in[18];
    const int* dst_p2c = (const int*)d_in[19];
    const int* src_c2p = (const int*)d_in[20];
    const int* dst_c2p = (const int*)d_in[21];

    const int N_A = in_sizes[0] / DD;   // 200000
    const int N_B = in_sizes[1] / DD;   // 400000
    const int E1  = in_sizes[14];       // 800000
    const int E2  = in_sizes[15];       // 800000

    float* outA = (float*)d_out;
    float* outB = outA + (size_t)N_A * DD;

    // ws layout: pre_B (bf16), pre_A (bf16), deg_A (f32), deg_B (f32)
    const size_t preB_bytes = (size_t)N_B * DD * 2;   // 102.4MB
    const size_t preA_bytes = (size_t)N_A * DD * 2;   // 51.2MB
    const size_t need = preB_bytes + preA_bytes + (size_t)(N_A + N_B) * 4; // ~156MB
    if (ws_size < need) return;

    unsigned int*   preB_w = (unsigned int*)d_ws;
    unsigned int*   preA_w = (unsigned int*)((char*)d_ws + preB_bytes);
    float*          deg_A  = (float*)((char*)d_ws + preB_bytes + preA_bytes);
    float*          deg_B  = deg_A + N_A;
    const unsigned short* preB_h = (const unsigned short*)preB_w;
    const unsigned short* preA_h = (const unsigned short*)preA_w;

    (void)hipMemsetAsync(d_ws, 0, need, stream);

    // fused scatter: first half of grid does A->B, second half B->A (overlapped)
    dim3 sblk(256), sgrd(2048);
    scatter2_kernel<<<sgrd, sblk, 0, stream>>>(feats_A, src_p2c, dst_p2c, u_p2c, preB_w, deg_B, E1,
                                               feats_B, src_c2p, dst_c2p, u_c2p, preA_w, deg_A, E2);

    dim3 tblk(512), tgrd(512);   // 2 blocks/CU, 16 waves/CU
    table_kernel<<<tgrd, tblk, 0, stream>>>(feats_A, preA_h, deg_A,
                                            Wself_A, bself_A, W_c2p, b_c2p,
                                            lnw_A, lnb_A, u_featA, outA, N_A);
    table_kernel<<<tgrd, tblk, 0, stream>>>(feats_B, preB_h, deg_B,
                                            Wself_B, bself_B, W_p2c, b_p2c,
                                            lnw_B, lnb_B, u_featB, outB, N_B);
}

// Round 19
// 924.663 us; speedup vs baseline: 1.5371x; 1.2456x over previous
//
#include <hip/hip_runtime.h>
#include <hip/hip_bf16.h>

#define DD 128

typedef __attribute__((ext_vector_type(8))) short short8;
typedef __attribute__((ext_vector_type(8))) unsigned short u16x8;
typedef __attribute__((ext_vector_type(4))) unsigned short u16x4;
typedef __attribute__((ext_vector_type(4))) float f32x4;

__device__ __forceinline__ unsigned short f2bf(float f) {
    union { unsigned int u; float f; } c; c.f = f;
    unsigned int u = c.u;
    unsigned int r = (u + 0x7FFFu + ((u >> 16) & 1u)) >> 16;
    return (unsigned short)r;
}
__device__ __forceinline__ float bf2f(unsigned short h) {
    union { unsigned int u; float f; } c; c.u = ((unsigned int)h) << 16; return c.f;
}

// -------- fused scatter (both directions in one launch, overlapped) --------
__device__ __forceinline__ void scatter_dir(const float* __restrict__ feats,
                                            const int* __restrict__ src,
                                            const int* __restrict__ dst,
                                            const float* __restrict__ u,
                                            unsigned int* __restrict__ pre,
                                            float* __restrict__ deg,
                                            int E, int wave, int lane, int nw)
{
    for (int e = wave; e < E; e += nw) {
        if (u[e] < 0.5f) {
            int s = src[e], d = dst[e];
            float2 x = *(const float2*)(feats + (size_t)s * DD + 2 * lane);
            unsigned int* p = pre + (size_t)d * 64 + lane;
#if defined(__HIP_DEVICE_COMPILE__)
            typedef short sv2 __attribute__((ext_vector_type(2)));
            sv2 v; v[0] = (short)f2bf(x.x); v[1] = (short)f2bf(x.y);
            __builtin_amdgcn_global_atomic_fadd_v2bf16((__attribute__((address_space(1))) sv2*)p, v);
#else
            (void)p; (void)x;
#endif
            if (lane == 0) unsafeAtomicAdd(deg + d, 1.0f);
        }
    }
}

__global__ void scatter2_kernel(const float* __restrict__ f1,
                                const int* __restrict__ s1, const int* __restrict__ d1,
                                const float* __restrict__ u1,
                                unsigned int* __restrict__ p1, float* __restrict__ g1, int E1,
                                const float* __restrict__ f2,
                                const int* __restrict__ s2, const int* __restrict__ d2,
                                const float* __restrict__ u2,
                                unsigned int* __restrict__ p2, float* __restrict__ g2, int E2)
{
    int half = gridDim.x >> 1;
    int lane = threadIdx.x & 63;
    int wavein = (blockIdx.x % half) * (blockDim.x >> 6) + (threadIdx.x >> 6);
    int nw = half * (blockDim.x >> 6);
    if (blockIdx.x < half) scatter_dir(f1, s1, d1, u1, p1, g1, E1, wavein, lane, nw);
    else                   scatter_dir(f2, s2, d2, u2, p2, g2, E2, wavein, lane, nw);
}

// -------- barrier-free table update; R16 structure + cross-iteration pipeline --------
// comb = X@Wself^T + bself + fmask*((pre/deg)@Wedge^T + (deg>0)*bedge)
// LN -> +residual -> SELU -> column-mask select
// Full-line loads for tile i+1 are issued into REGISTERS before tile i's
// compute; regs are staged to per-wave LDS tiles at loop top. HBM latency of
// the next tile hides under current tile's MFMA+epilogue.
__global__ __launch_bounds__(512, 1)
void table_kernel(const float* __restrict__ feats,
                  const unsigned short* __restrict__ pre,   // bf16
                  const float* __restrict__ deg,
                  const float* __restrict__ Wself,
                  const float* __restrict__ bself,
                  const float* __restrict__ Wedge,
                  const float* __restrict__ bedge,
                  const float* __restrict__ lnw,
                  const float* __restrict__ lnb,
                  const float* __restrict__ ufeat,
                  float* __restrict__ out,
                  int N)
{
    __shared__ __align__(16) unsigned short wlds[2 * 16384];  // 64KB weights (bf16, swizzled)
    __shared__ __align__(16) char xsall[8 * 8192];            // 64KB: 8 waves x (4KB X + 4KB pre)

    const int tid = threadIdx.x;

    // ---- one-time weight staging: f32 -> bf16, XOR-swizzled (addr ^= (j&7)<<4) ----
    {
        int j  = tid >> 2;        // W row (output col) 0..127
        int kq = tid & 3;         // k quarter
        float fm = ufeat[j] < 0.3f ? 1.0f : 0.0f;
        const float* wsrow = Wself + j * DD + kq * 32;
        const float* werow = Wedge + j * DD + kq * 32;
        char* lbs = (char*)wlds;
        #pragma unroll
        for (int c = 0; c < 4; ++c) {
            unsigned short tS[8], tE[8];
            #pragma unroll
            for (int i = 0; i < 8; ++i) {
                tS[i] = f2bf(wsrow[c * 8 + i]);
                tE[i] = f2bf(werow[c * 8 + i] * fm);
            }
            int addr = (j * 256 + kq * 64 + c * 16) ^ ((j & 7) << 4);
            *(short8*)(lbs + addr)         = *(short8*)tS;
            *(short8*)(lbs + 32768 + addr) = *(short8*)tE;
        }
    }
    __syncthreads();   // only barrier in the kernel

    const int wave = tid >> 6;
    const int lane = tid & 63;
    const int lj = lane & 15;
    const int lk = lane >> 4;

    // per-lane column constants (col = ct*16 + lj)
    float bs[8], bem[8], lw[8], lb[8];
    unsigned fmask = 0;
    #pragma unroll
    for (int ct = 0; ct < 8; ++ct) {
        int col = ct * 16 + lj;
        bool fm = ufeat[col] < 0.3f;
        bs[ct]  = bself[col];
        bem[ct] = fm ? bedge[col] : 0.0f;
        lw[ct]  = lnw[col];
        lb[ct]  = lnb[col];
        fmask |= (fm ? 1u : 0u) << ct;
    }

    char* xs  = xsall + wave * 8192;        // bf16 X tile   [16][128]
    char* ps  = xs + 4096;                  // bf16 pre tile [16][128]
    const char* wb = (const char*)wlds;
    const int ldb  = lj * 256 + lk * 16;
    const int xorv = (lj & 7) << 4;

    const int frow = lane >> 5;             // feats-load row parity
    const int fc4  = lane & 31;             // feats-load 16B chunk
    const int prow = lane >> 4;             // pre-load row parity (4 rows/instr)
    const int pch  = lane & 15;             // pre-load 16B chunk

    const int ntiles = N >> 4;
    const int stride = gridDim.x * 8;
    int tile = blockIdx.x * 8 + wave;

    // ---- pipeline registers: full-line-mapped loads for the CURRENT tile ----
    f32x4 xr[8];
    u16x8 pw[4];
    float dg = 0.f;

    if (tile < ntiles) {
        int row0 = tile << 4;
        #pragma unroll
        for (int j = 0; j < 8; ++j) {
            int row = j * 2 + frow;
            xr[j] = *(const f32x4*)(feats + (size_t)(row0 + row) * DD + fc4 * 4);
        }
        #pragma unroll
        for (int c = 0; c < 4; ++c) {
            int row = c * 4 + prow;
            pw[c] = *(const u16x8*)(pre + (size_t)(row0 + row) * DD + pch * 8);
        }
        dg = deg[row0 + lj];
    }

    while (tile < ntiles) {
        int row0 = tile << 4;
        int nxt  = tile + stride;

        // ---- stage current regs -> LDS (full-line mappings, swizzled) ----
        #pragma unroll
        for (int j = 0; j < 8; ++j) {
            int row = j * 2 + frow;
            unsigned short t4[4];
            #pragma unroll
            for (int i = 0; i < 4; ++i) t4[i] = f2bf(xr[j][i]);
            *(u16x4*)(xs + row * 256 + ((fc4 * 8) ^ ((row & 7) << 4))) = *(u16x4*)t4;
        }
        #pragma unroll
        for (int c = 0; c < 4; ++c) {
            int row = c * 4 + prow;
            *(u16x8*)(ps + row * 256 + ((pch * 16) ^ ((row & 7) << 4))) = pw[c];
        }
        float dgr = dg;

        // ---- issue NEXT tile's global loads (fly under current compute) ----
        if (nxt < ntiles) {
            int nrow0 = nxt << 4;
            #pragma unroll
            for (int j = 0; j < 8; ++j) {
                int row = j * 2 + frow;
                xr[j] = *(const f32x4*)(feats + (size_t)(nrow0 + row) * DD + fc4 * 4);
            }
            #pragma unroll
            for (int c = 0; c < 4; ++c) {
                int row = c * 4 + prow;
                pw[c] = *(const u16x8*)(pre + (size_t)(nrow0 + row) * DD + pch * 8);
            }
            dg = deg[nrow0 + lj];
        }

        float invd  = 1.0f / fmaxf(dgr, 1.0f);
        float dpown = dgr > 0.5f ? 1.0f : 0.0f;

        // ---- fragments from LDS; pre scaled by invd at read ----
        short8 xf[4], pf[4];
        #pragma unroll
        for (int t = 0; t < 4; ++t) {
            int a = (ldb + t * 64) ^ xorv;
            xf[t] = *(const short8*)(xs + a);
            u16x8 pv = *(const u16x8*)(ps + a);
            unsigned short tp[8];
            #pragma unroll
            for (int i = 0; i < 8; ++i) tp[i] = f2bf(bf2f(pv[i]) * invd);
            pf[t] = *(short8*)tp;
        }

        f32x4 acc[8];
        #pragma unroll
        for (int ct = 0; ct < 8; ++ct) { f32x4 z = {0.f,0.f,0.f,0.f}; acc[ct] = z; }

        #pragma unroll
        for (int t = 0; t < 4; ++t) {
            int a0 = (ldb + t * 64) ^ xorv;
            #pragma unroll
            for (int ct = 0; ct < 8; ++ct) {
                short8 ws = *(const short8*)(wb + ct * 4096 + a0);
                short8 we = *(const short8*)(wb + 32768 + ct * 4096 + a0);
                acc[ct] = __builtin_amdgcn_mfma_f32_16x16x32_bf16(xf[t], ws, acc[ct], 0, 0, 0);
                acc[ct] = __builtin_amdgcn_mfma_f32_16x16x32_bf16(pf[t], we, acc[ct], 0, 0, 0);
            }
        }

        // ---- epilogue; D layout: col = ct*16+lj, row-in-tile = lk*4+q ----
        #pragma unroll
        for (int q = 0; q < 4; ++q) {
            int rrl = lk * 4 + q;
            float degpos = __shfl(dpown, rrl, 64);   // lanes 0..15 hold rows 0..15
            float val[8];
            float s = 0.f, s2 = 0.f;
            #pragma unroll
            for (int ct = 0; ct < 8; ++ct) {
                float v = acc[ct][q] + bs[ct] + degpos * bem[ct];
                val[ct] = v; s += v; s2 += v * v;
            }
            #pragma unroll
            for (int m = 1; m < 16; m <<= 1) {
                s  += __shfl_xor(s,  m, 64);
                s2 += __shfl_xor(s2, m, 64);
            }
            float mu   = s * (1.0f / 128.0f);
            float var  = s2 * (1.0f / 128.0f) - mu * mu;
            float rstd = rsqrtf(var + 1e-5f);
            #pragma unroll
            for (int ct = 0; ct < 8; ++ct) {
                int col = ct * 16 + lj;
                int ra  = rrl * 256 + ((col * 2) ^ ((rrl & 7) << 4));
                float fres = bf2f(*(const unsigned short*)(xs + ra));
                float ln = (val[ct] - mu) * rstd * lw[ct] + lb[ct];
                float x = ln + fres;
                float selu = x > 0.f ? 1.0507009873554805f * x
                                     : 1.0507009873554805f * 1.6732632423543772f * (expf(x) - 1.0f);
                float o = ((fmask >> ct) & 1) ? selu : fres;
                *(unsigned short*)(xs + ra) = f2bf(o);   // in-place 2B
            }
        }

        // ---- full-line readback + plain vector stores (1KB contiguous/instr) ----
        #pragma unroll
        for (int j = 0; j < 8; ++j) {
            int row = j * 2 + frow;
            u16x4 ov = *(const u16x4*)(xs + row * 256 + ((fc4 * 8) ^ ((row & 7) << 4)));
            f32x4 o;
            #pragma unroll
            for (int i = 0; i < 4; ++i) o[i] = bf2f(ov[i]);
            *(f32x4*)(out + (size_t)(row0 + row) * DD + fc4 * 4) = o;
        }

        tile = nxt;
    }
}

extern "C" void kernel_launch(void* const* d_in, const int* in_sizes, int n_in,
                              void* d_out, int out_size, void* d_ws, size_t ws_size,
                              hipStream_t stream)
{
    const float* feats_A = (const float*)d_in[0];
    const float* feats_B = (const float*)d_in[1];
    const float* W_p2c   = (const float*)d_in[2];
    const float* b_p2c   = (const float*)d_in[3];
    const float* W_c2p   = (const float*)d_in[4];
    const float* b_c2p   = (const float*)d_in[5];
    const float* Wself_A = (const float*)d_in[6];
    const float* bself_A = (const float*)d_in[7];
    const float* lnw_A   = (const float*)d_in[8];
    const float* lnb_A   = (const float*)d_in[9];
    const float* Wself_B = (const float*)d_in[10];
    const float* bself_B = (const float*)d_in[11];
    const float* lnw_B   = (const float*)d_in[12];
    const float* lnb_B   = (const float*)d_in[13];
    const float* u_p2c   = (const float*)d_in[14];
    const float* u_c2p   = (const float*)d_in[15];
    const float* u_featA = (const float*)d_in[16];
    const float* u_featB = (const float*)d_in[17];
    const int* src_p2c = (const int*)d_in[18];
    const int* dst_p2c = (const int*)d_in[19];
    const int* src_c2p = (const int*)d_in[20];
    const int* dst_c2p = (const int*)d_in[21];

    const int N_A = in_sizes[0] / DD;   // 200000
    const int N_B = in_sizes[1] / DD;   // 400000
    const int E1  = in_sizes[14];       // 800000
    const int E2  = in_sizes[15];       // 800000

    float* outA = (float*)d_out;
    float* outB = outA + (size_t)N_A * DD;

    // ws layout: pre_B (bf16), pre_A (bf16), deg_A (f32), deg_B (f32)
    const size_t preB_bytes = (size_t)N_B * DD * 2;   // 102.4MB
    const size_t preA_bytes = (size_t)N_A * DD * 2;   // 51.2MB
    const size_t need = preB_bytes + preA_bytes + (size_t)(N_A + N_B) * 4; // ~156MB
    if (ws_size < need) return;

    unsigned int*   preB_w = (unsigned int*)d_ws;
    unsigned int*   preA_w = (unsigned int*)((char*)d_ws + preB_bytes);
    float*          deg_A  = (float*)((char*)d_ws + preB_bytes + preA_bytes);
    float*          deg_B  = deg_A + N_A;
    const unsigned short* preB_h = (const unsigned short*)preB_w;
    const unsigned short* preA_h = (const unsigned short*)preA_w;

    (void)hipMemsetAsync(d_ws, 0, need, stream);

    // fused scatter: first half of grid does A->B, second half B->A (overlapped)
    dim3 sblk(256), sgrd(2048);
    scatter2_kernel<<<sgrd, sblk, 0, stream>>>(feats_A, src_p2c, dst_p2c, u_p2c, preB_w, deg_B, E1,
                                               feats_B, src_c2p, dst_c2p, u_c2p, preA_w, deg_A, E2);

    dim3 tblk(512), tgrd(256);   // 1 block per CU, 8 waves/CU
    table_kernel<<<tgrd, tblk, 0, stream>>>(feats_A, preA_h, deg_A,
                                            Wself_A, bself_A, W_c2p, b_c2p,
                                            lnw_A, lnb_A, u_featA, outA, N_A);
    table_kernel<<<tgrd, tblk, 0, stream>>>(feats_B, preB_h, deg_B,
                                            Wself_B, bself_B, W_p2c, b_p2c,
                                            lnw_B, lnb_B, u_featB, outB, N_B);
}

// Round 20
// 791.626 us; speedup vs baseline: 1.7955x; 1.1681x over previous
//
#include <hip/hip_runtime.h>
#include <hip/hip_bf16.h>

#define DD 128

typedef __attribute__((ext_vector_type(8))) short short8;
typedef __attribute__((ext_vector_type(8))) unsigned short u16x8;
typedef __attribute__((ext_vector_type(4))) unsigned short u16x4;
typedef __attribute__((ext_vector_type(4))) float f32x4;

__device__ __forceinline__ unsigned short f2bf(float f) {
    union { unsigned int u; float f; } c; c.f = f;
    unsigned int u = c.u;
    unsigned int r = (u + 0x7FFFu + ((u >> 16) & 1u)) >> 16;
    return (unsigned short)r;
}
__device__ __forceinline__ float bf2f(unsigned short h) {
    union { unsigned int u; float f; } c; c.u = ((unsigned int)h) << 16; return c.f;
}

__device__ __forceinline__ void pk_atomic(unsigned int* p, float a, float b) {
#if defined(__HIP_DEVICE_COMPILE__)
    typedef short sv2 __attribute__((ext_vector_type(2)));
    sv2 v; v[0] = (short)f2bf(a); v[1] = (short)f2bf(b);
    __builtin_amdgcn_global_atomic_fadd_v2bf16((__attribute__((address_space(1))) sv2*)p, v);
#else
    (void)p; (void)a; (void)b;
#endif
}

// -------- fused scatter: wave-batched edges (64 u/src/dst per 3 coalesced loads),
//          ballot-compacted kept set, 2-deep gather/atomic unroll --------
__device__ __forceinline__ void scatter_dir(const float* __restrict__ feats,
                                            const int* __restrict__ src,
                                            const int* __restrict__ dst,
                                            const float* __restrict__ u,
                                            unsigned int* __restrict__ pre,
                                            float* __restrict__ deg,
                                            int E, int gwave, int lane, int nw)
{
    for (int base = gwave * 64; base < E; base += nw * 64) {
        int e = base + lane;
        bool keep = false;
        int s = 0, d = 0;
        if (e < E) {
            keep = (u[e] < 0.5f);
            s = src[e];
            d = dst[e];
        }
        unsigned long long mask = __ballot(keep);
        while (mask) {
            int k0 = __ffsll((unsigned long long)mask) - 1;
            mask &= mask - 1;
            int k1 = -1;
            if (mask) { k1 = __ffsll((unsigned long long)mask) - 1; mask &= mask - 1; }

            int s0 = __shfl(s, k0, 64), d0 = __shfl(d, k0, 64);
            float2 x0 = *(const float2*)(feats + (size_t)s0 * DD + 2 * lane);
            int s1 = 0, d1 = 0;
            float2 x1 = {0.f, 0.f};
            if (k1 >= 0) {
                s1 = __shfl(s, k1, 64); d1 = __shfl(d, k1, 64);
                x1 = *(const float2*)(feats + (size_t)s1 * DD + 2 * lane);
            }

            pk_atomic(pre + (size_t)d0 * 64 + lane, x0.x, x0.y);
            if (lane == 0) unsafeAtomicAdd(deg + d0, 1.0f);
            if (k1 >= 0) {
                pk_atomic(pre + (size_t)d1 * 64 + lane, x1.x, x1.y);
                if (lane == 0) unsafeAtomicAdd(deg + d1, 1.0f);
            }
        }
    }
}

__global__ void scatter2_kernel(const float* __restrict__ f1,
                                const int* __restrict__ s1, const int* __restrict__ d1,
                                const float* __restrict__ u1,
                                unsigned int* __restrict__ p1, float* __restrict__ g1, int E1,
                                const float* __restrict__ f2,
                                const int* __restrict__ s2, const int* __restrict__ d2,
                                const float* __restrict__ u2,
                                unsigned int* __restrict__ p2, float* __restrict__ g2, int E2)
{
    int half = gridDim.x >> 1;
    int lane = threadIdx.x & 63;
    int wavein = (blockIdx.x % half) * (blockDim.x >> 6) + (threadIdx.x >> 6);
    int nw = half * (blockDim.x >> 6);
    if (blockIdx.x < half) scatter_dir(f1, s1, d1, u1, p1, g1, E1, wavein, lane, nw);
    else                   scatter_dir(f2, s2, d2, u2, p2, g2, E2, wavein, lane, nw);
}

// -------- barrier-free table update; EXACT R16 structure (best: 373us table_B) --------
__global__ __launch_bounds__(512, 2)
void table_kernel(const float* __restrict__ feats,
                  const unsigned short* __restrict__ pre,   // bf16
                  const float* __restrict__ deg,
                  const float* __restrict__ Wself,
                  const float* __restrict__ bself,
                  const float* __restrict__ Wedge,
                  const float* __restrict__ bedge,
                  const float* __restrict__ lnw,
                  const float* __restrict__ lnb,
                  const float* __restrict__ ufeat,
                  float* __restrict__ out,
                  int N)
{
    __shared__ __align__(16) unsigned short wlds[2 * 16384];  // 64KB weights (bf16, swizzled)
    __shared__ __align__(16) char xsall[8 * 8192];            // 64KB: 8 waves x (4KB X + 4KB pre)

    const int tid = threadIdx.x;

    // ---- one-time weight staging: f32 -> bf16, XOR-swizzled (addr ^= (j&7)<<4) ----
    {
        int j  = tid >> 2;        // W row (output col) 0..127
        int kq = tid & 3;         // k quarter
        float fm = ufeat[j] < 0.3f ? 1.0f : 0.0f;
        const float* wsrow = Wself + j * DD + kq * 32;
        const float* werow = Wedge + j * DD + kq * 32;
        char* lbs = (char*)wlds;
        #pragma unroll
        for (int c = 0; c < 4; ++c) {
            unsigned short tS[8], tE[8];
            #pragma unroll
            for (int i = 0; i < 8; ++i) {
                tS[i] = f2bf(wsrow[c * 8 + i]);
                tE[i] = f2bf(werow[c * 8 + i] * fm);
            }
            int addr = (j * 256 + kq * 64 + c * 16) ^ ((j & 7) << 4);
            *(short8*)(lbs + addr)         = *(short8*)tS;
            *(short8*)(lbs + 32768 + addr) = *(short8*)tE;
        }
    }
    __syncthreads();   // only barrier in the kernel

    const int wave = tid >> 6;
    const int lane = tid & 63;
    const int lj = lane & 15;
    const int lk = lane >> 4;

    // per-lane column constants (col = ct*16 + lj)
    float bs[8], bem[8], lw[8], lb[8];
    unsigned fmask = 0;
    #pragma unroll
    for (int ct = 0; ct < 8; ++ct) {
        int col = ct * 16 + lj;
        bool fm = ufeat[col] < 0.3f;
        bs[ct]  = bself[col];
        bem[ct] = fm ? bedge[col] : 0.0f;
        lw[ct]  = lnw[col];
        lb[ct]  = lnb[col];
        fmask |= (fm ? 1u : 0u) << ct;
    }

    char* xs  = xsall + wave * 8192;        // bf16 X tile   [16][128]
    char* ps  = xs + 4096;                  // bf16 pre tile [16][128]
    const char* wb = (const char*)wlds;
    const int ldb  = lj * 256 + lk * 16;
    const int xorv = (lj & 7) << 4;

    const int frow = lane >> 5;             // feats-load row parity
    const int fc4  = lane & 31;             // feats-load 16B chunk
    const int prow = lane >> 4;             // pre-load row parity (4 rows/instr)
    const int pch  = lane & 15;             // pre-load 16B chunk

    const int ntiles = N >> 4;
    for (int tile = blockIdx.x * 8 + wave; tile < ntiles; tile += gridDim.x * 8) {
        int row0 = tile << 4;

        // ---- feats: 8 full-line PLAIN loads (2 rows x 32 lanes contiguous) ----
        #pragma unroll
        for (int j = 0; j < 8; ++j) {
            int row = j * 2 + frow;
            f32x4 v = *(const f32x4*)(feats + (size_t)(row0 + row) * DD + fc4 * 4);
            unsigned short t4[4];
            #pragma unroll
            for (int i = 0; i < 4; ++i) t4[i] = f2bf(v[i]);
            *(u16x4*)(xs + row * 256 + ((fc4 * 8) ^ ((row & 7) << 4))) = *(u16x4*)t4;
        }
        // ---- pre: 4 full-line PLAIN loads (4 rows x 16 lanes contiguous) ----
        #pragma unroll
        for (int c = 0; c < 4; ++c) {
            int row = c * 4 + prow;
            u16x8 v = *(const u16x8*)(pre + (size_t)(row0 + row) * DD + pch * 8);
            *(u16x8*)(ps + row * 256 + ((pch * 16) ^ ((row & 7) << 4))) = v;
        }

        float dgr  = deg[row0 + lj];
        float invd = 1.0f / fmaxf(dgr, 1.0f);
        float dpown = dgr > 0.5f ? 1.0f : 0.0f;

        // ---- fragments from LDS; pre scaled by invd at read ----
        short8 xf[4], pf[4];
        #pragma unroll
        for (int t = 0; t < 4; ++t) {
            int a = (ldb + t * 64) ^ xorv;
            xf[t] = *(const short8*)(xs + a);
            u16x8 pv = *(const u16x8*)(ps + a);
            unsigned short tp[8];
            #pragma unroll
            for (int i = 0; i < 8; ++i) tp[i] = f2bf(bf2f(pv[i]) * invd);
            pf[t] = *(short8*)tp;
        }

        f32x4 acc[8];
        #pragma unroll
        for (int ct = 0; ct < 8; ++ct) { f32x4 z = {0.f,0.f,0.f,0.f}; acc[ct] = z; }

        #pragma unroll
        for (int t = 0; t < 4; ++t) {
            int a0 = (ldb + t * 64) ^ xorv;
            #pragma unroll
            for (int ct = 0; ct < 8; ++ct) {
                short8 ws = *(const short8*)(wb + ct * 4096 + a0);
                short8 we = *(const short8*)(wb + 32768 + ct * 4096 + a0);
                acc[ct] = __builtin_amdgcn_mfma_f32_16x16x32_bf16(xf[t], ws, acc[ct], 0, 0, 0);
                acc[ct] = __builtin_amdgcn_mfma_f32_16x16x32_bf16(pf[t], we, acc[ct], 0, 0, 0);
            }
        }

        // ---- epilogue; D layout: col = ct*16+lj, row-in-tile = lk*4+q ----
        #pragma unroll
        for (int q = 0; q < 4; ++q) {
            int rrl = lk * 4 + q;
            float degpos = __shfl(dpown, rrl, 64);   // lanes 0..15 hold rows 0..15
            float val[8];
            float s = 0.f, s2 = 0.f;
            #pragma unroll
            for (int ct = 0; ct < 8; ++ct) {
                float v = acc[ct][q] + bs[ct] + degpos * bem[ct];
                val[ct] = v; s += v; s2 += v * v;
            }
            #pragma unroll
            for (int m = 1; m < 16; m <<= 1) {
                s  += __shfl_xor(s,  m, 64);
                s2 += __shfl_xor(s2, m, 64);
            }
            float mu   = s * (1.0f / 128.0f);
            float var  = s2 * (1.0f / 128.0f) - mu * mu;
            float rstd = rsqrtf(var + 1e-5f);
            #pragma unroll
            for (int ct = 0; ct < 8; ++ct) {
                int col = ct * 16 + lj;
                int ra  = rrl * 256 + ((col * 2) ^ ((rrl & 7) << 4));
                float fres = bf2f(*(const unsigned short*)(xs + ra));
                float ln = (val[ct] - mu) * rstd * lw[ct] + lb[ct];
                float x = ln + fres;
                float selu = x > 0.f ? 1.0507009873554805f * x
                                     : 1.0507009873554805f * 1.6732632423543772f * (expf(x) - 1.0f);
                float o = ((fmask >> ct) & 1) ? selu : fres;
                *(unsigned short*)(xs + ra) = f2bf(o);   // in-place 2B
            }
        }

        // ---- full-line readback + plain vector stores (1KB contiguous/instr) ----
        #pragma unroll
        for (int j = 0; j < 8; ++j) {
            int row = j * 2 + frow;
            u16x4 ov = *(const u16x4*)(xs + row * 256 + ((fc4 * 8) ^ ((row & 7) << 4)));
            f32x4 o;
            #pragma unroll
            for (int i = 0; i < 4; ++i) o[i] = bf2f(ov[i]);
            *(f32x4*)(out + (size_t)(row0 + row) * DD + fc4 * 4) = o;
        }
    }
}

extern "C" void kernel_launch(void* const* d_in, const int* in_sizes, int n_in,
                              void* d_out, int out_size, void* d_ws, size_t ws_size,
                              hipStream_t stream)
{
    const float* feats_A = (const float*)d_in[0];
    const float* feats_B = (const float*)d_in[1];
    const float* W_p2c   = (const float*)d_in[2];
    const float* b_p2c   = (const float*)d_in[3];
    const float* W_c2p   = (const float*)d_in[4];
    const float* b_c2p   = (const float*)d_in[5];
    const float* Wself_A = (const float*)d_in[6];
    const float* bself_A = (const float*)d_in[7];
    const float* lnw_A   = (const float*)d_in[8];
    const float* lnb_A   = (const float*)d_in[9];
    const float* Wself_B = (const float*)d_in[10];
    const float* bself_B = (const float*)d_in[11];
    const float* lnw_B   = (const float*)d_in[12];
    const float* lnb_B   = (const float*)d_in[13];
    const float* u_p2c   = (const float*)d_in[14];
    const float* u_c2p   = (const float*)d_in[15];
    const float* u_featA = (const float*)d_in[16];
    const float* u_featB = (const float*)d_in[17];
    const int* src_p2c = (const int*)d_in[18];
    const int* dst_p2c = (const int*)d_in[19];
    const int* src_c2p = (const int*)d_in[20];
    const int* dst_c2p = (const int*)d_in[21];

    const int N_A = in_sizes[0] / DD;   // 200000
    const int N_B = in_sizes[1] / DD;   // 400000
    const int E1  = in_sizes[14];       // 800000
    const int E2  = in_sizes[15];       // 800000

    float* outA = (float*)d_out;
    float* outB = outA + (size_t)N_A * DD;

    // ws layout: pre_B (bf16), pre_A (bf16), deg_A (f32), deg_B (f32)
    const size_t preB_bytes = (size_t)N_B * DD * 2;   // 102.4MB
    const size_t preA_bytes = (size_t)N_A * DD * 2;   // 51.2MB
    const size_t need = preB_bytes + preA_bytes + (size_t)(N_A + N_B) * 4; // ~156MB
    if (ws_size < need) return;

    unsigned int*   preB_w = (unsigned int*)d_ws;
    unsigned int*   preA_w = (unsigned int*)((char*)d_ws + preB_bytes);
    float*          deg_A  = (float*)((char*)d_ws + preB_bytes + preA_bytes);
    float*          deg_B  = deg_A + N_A;
    const unsigned short* preB_h = (const unsigned short*)preB_w;
    const unsigned short* preA_h = (const unsigned short*)preA_w;

    (void)hipMemsetAsync(d_ws, 0, need, stream);

    // fused scatter: first half of grid does A->B, second half B->A (overlapped)
    dim3 sblk(256), sgrd(2048);
    scatter2_kernel<<<sgrd, sblk, 0, stream>>>(feats_A, src_p2c, dst_p2c, u_p2c, preB_w, deg_B, E1,
                                               feats_B, src_c2p, dst_c2p, u_c2p, preA_w, deg_A, E2);

    dim3 tblk(512), tgrd(256);   // 1 block per CU, 8 waves/CU, 128 VGPR
    table_kernel<<<tgrd, tblk, 0, stream>>>(feats_A, preA_h, deg_A,
                                            Wself_A, bself_A, W_c2p, b_c2p,
                                            lnw_A, lnb_A, u_featA, outA, N_A);
    table_kernel<<<tgrd, tblk, 0, stream>>>(feats_B, preB_h, deg_B,
                                            Wself_B, bself_B, W_p2c, b_p2c,
                                            lnw_B, lnb_B, u_featB, outB, N_B);
}